// Round 3
// baseline (561.849 us; speedup 1.0000x reference)
//
#include <hip/hip_runtime.h>
#include <hip/hip_bf16.h>

#define N_NODES 20000
#define E_EDGES 640000
#define DIM 128
#define CAP 192
#define EPB 64    // edges per block in edge_kernel
#define NPB 8     // nodes per block in node_kernel
#define XST 264   // padded ushort stride for [64][256] LDS tile

typedef __attribute__((ext_vector_type(8))) short bf16x8;
typedef __attribute__((ext_vector_type(4))) float f32x4;

__device__ __forceinline__ float fsilu(float x) { return x / (1.f + __expf(-x)); }
__device__ __forceinline__ float fsig(float x)  { return 1.f / (1.f + __expf(-x)); }

__device__ __forceinline__ unsigned short f2bf(float x) {
    union { float f; unsigned u; } v; v.f = x;
    unsigned r = (v.u + 0x7fffu + ((v.u >> 16) & 1u)) >> 16;
    return (unsigned short)r;
}
__device__ __forceinline__ float bf2f(unsigned short s) {
    union { unsigned u; float f; } v; v.u = ((unsigned)s) << 16;
    return v.f;
}
// pack two floats to packed bf16 {lo,hi} with round-half-up: 2 adds + 1 v_perm
__device__ __forceinline__ unsigned pack_bf16(float lo, float hi) {
    union { float f; unsigned u; } a, b; a.f = lo; b.f = hi;
    unsigned ul = a.u + 0x8000u, uh = b.u + 0x8000u;
    return __builtin_amdgcn_perm(uh, ul, 0x07060302u);  // D = {ul.b2,ul.b3,uh.b2,uh.b3}
}

// ---------------- Kernel 0: weight prep ----------------
// w1b: [256][256] bf16 (drop last col); w1last: fp32 last col; w2b: [128][256] bf16
// with k PERMUTED to match the packed a1 store: within each 32-chunk b,
// position b+2l <- k=b+l ; position b+2l+1 <- k=b+16+l.
__global__ void prep_kernel(const float* __restrict__ w1, const float* __restrict__ w2,
                            unsigned short* __restrict__ w1b, float* __restrict__ w1last,
                            unsigned short* __restrict__ w2b) {
    int i = blockIdx.x * blockDim.x + threadIdx.x;
    int stride = gridDim.x * blockDim.x;
    for (int idx = i; idx < 256 * 256; idx += stride) {
        int o = idx >> 8, k = idx & 255;
        w1b[idx] = f2bf(w1[o * 257 + k]);
    }
    for (int idx = i; idx < 128 * 256; idx += stride) {
        int n2 = idx >> 8, p = idx & 255;
        int b = p & ~31, off = p & 31;
        int ksrc = b + (off >> 1) + ((off & 1) << 4);
        w2b[idx] = f2bf(w2[n2 * 256 + ksrc]);
    }
    for (int idx = i; idx < 256; idx += stride)
        w1last[idx] = w1[idx * 257 + 256];
}

// ---------------- Kernel 1: x = h @ lin_w.T + lin_b ----------------
__global__ void lin_kernel(const float* __restrict__ h, const float* __restrict__ w,
                           const float* __restrict__ b, float* __restrict__ x,
                           unsigned short* __restrict__ xb) {
    __shared__ float hs[16][128];
    int t = threadIdx.x;
    int n0 = blockIdx.x * 16;
#pragma unroll
    for (int j = 0; j < 16; ++j) hs[j][t] = h[(size_t)(n0 + j) * DIM + t];
    __syncthreads();
    float acc[16];
#pragma unroll
    for (int j = 0; j < 16; ++j) acc[j] = 0.f;
    for (int kc = 0; kc < 128; kc += 4) {
        float4 wv = *(const float4*)&w[(size_t)t * DIM + kc];
#pragma unroll
        for (int j = 0; j < 16; ++j)
            acc[j] += wv.x * hs[j][kc] + wv.y * hs[j][kc + 1] + wv.z * hs[j][kc + 2] + wv.w * hs[j][kc + 3];
    }
    float bias = b[t];
#pragma unroll
    for (int j = 0; j < 16; ++j) {
        float v = acc[j] + bias;
        x[(size_t)(n0 + j) * DIM + t] = v;
        xb[(size_t)(n0 + j) * DIM + t] = f2bf(v);
    }
}

// ---------------- adjacency build ----------------
__global__ void adj_kernel(const int* __restrict__ edges, int* __restrict__ cnt,
                           int* __restrict__ adj, int E) {
    int e = blockIdx.x * blockDim.x + threadIdx.x;
    if (e < E) {
        int r = edges[e];
        int slot = atomicAdd(&cnt[r], 1);
        if (slot < CAP) adj[(size_t)r * CAP + slot] = e;
    }
}

// ---------------- Kernel 2: edge MLP -> att[E] ----------------
// 512 threads (8 waves), 64 edges/block; waves split N. Single [64][XST] tile
// (xcat, then a1 with permuted columns). Packed b32 a1 stores, conflict-free.
__global__ __launch_bounds__(512, 4) void edge_kernel(
    const unsigned short* __restrict__ xb,
    const float* __restrict__ dist, const float* __restrict__ emask,
    const int* __restrict__ edges,
    const unsigned short* __restrict__ w1b, const float* __restrict__ w1last,
    const float* __restrict__ b1,
    const unsigned short* __restrict__ w2b, const float* __restrict__ b2,
    const float* __restrict__ w3, const float* __restrict__ b3v,
    float* __restrict__ att, int E) {
    __shared__ unsigned short buf[EPB * XST];
    __shared__ float part[8][EPB];
    __shared__ float dvals[EPB];
    __shared__ int ridx[EPB], cidx[EPB];

    int tid = threadIdx.x;
    int eb = blockIdx.x * EPB;

    if (tid < EPB) {
        int e = eb + tid;
        ridx[tid] = edges[e];
        cidx[tid] = edges[E + e];
        dvals[tid] = dist[e] * emask[e];
    }
    __syncthreads();

#pragma unroll
    for (int i = 0; i < 4; ++i) {
        int c = tid + 512 * i;
        int r = c >> 5;
        int cb = (c & 31) * 8;
        const unsigned short* src;
        if (cb < 128) src = xb + (size_t)ridx[r] * DIM + cb;
        else          src = xb + (size_t)cidx[r] * DIM + (cb - 128);
        *(bf16x8*)&buf[r * XST + cb] = *(const bf16x8*)src;
    }

    int wave = tid >> 6, lane = tid & 63;
    int lrow = lane & 15, quad = lane >> 4;
    int nb = wave * 32;

    // hoist epilogue constants (overlap with barrier/K-loop)
    float bias0 = b1[nb + lrow], bias1 = b1[nb + 16 + lrow];
    float wl0 = w1last[nb + lrow], wl1 = w1last[nb + 16 + lrow];
    int n2 = wave * 16 + lrow;
    float bias2 = b2[n2];
    float w3v = w3[n2];

    __syncthreads();

    // ---- layer 1: wave covers 32 of 256 N
    f32x4 z = {0.f, 0.f, 0.f, 0.f};
    f32x4 acc1[4][2];
#pragma unroll
    for (int mt = 0; mt < 4; ++mt)
#pragma unroll
        for (int nt = 0; nt < 2; ++nt) acc1[mt][nt] = z;

    for (int kk = 0; kk < 8; ++kk) {
        int ka = kk * 32 + quad * 8;
        bf16x8 a[4];
#pragma unroll
        for (int mt = 0; mt < 4; ++mt)
            a[mt] = *(bf16x8*)&buf[(mt * 16 + lrow) * XST + ka];
#pragma unroll
        for (int nt = 0; nt < 2; ++nt) {
            int n = nb + nt * 16 + lrow;
            bf16x8 bfrag = *(const bf16x8*)&w1b[(size_t)n * 256 + ka];
#pragma unroll
            for (int mt = 0; mt < 4; ++mt)
                acc1[mt][nt] = __builtin_amdgcn_mfma_f32_16x16x32_bf16(a[mt], bfrag, acc1[mt][nt], 0, 0, 0);
        }
    }
    __syncthreads();   // xcat dead; buf becomes permuted a1

    int colbase = nb + 2 * lrow;
#pragma unroll
    for (int mt = 0; mt < 4; ++mt) {
#pragma unroll
        for (int r = 0; r < 4; ++r) {
            int m = mt * 16 + quad * 4 + r;
            float dv = dvals[m];
            float v0 = fsilu(acc1[mt][0][r] + bias0 + dv * wl0);
            float v1 = fsilu(acc1[mt][1][r] + bias1 + dv * wl1);
            *(unsigned*)&buf[m * XST + colbase] = pack_bf16(v0, v1);
        }
    }
    __syncthreads();

    // ---- layer 2: wave covers 16 of 128 N2 (k-order permuted on both sides)
    f32x4 acc2[4];
#pragma unroll
    for (int mt = 0; mt < 4; ++mt) acc2[mt] = z;

    for (int kk = 0; kk < 8; ++kk) {
        int ka = kk * 32 + quad * 8;
        bf16x8 bfrag = *(const bf16x8*)&w2b[(size_t)n2 * 256 + ka];
#pragma unroll
        for (int mt = 0; mt < 4; ++mt) {
            bf16x8 a = *(bf16x8*)&buf[(mt * 16 + lrow) * XST + ka];
            acc2[mt] = __builtin_amdgcn_mfma_f32_16x16x32_bf16(a, bfrag, acc2[mt], 0, 0, 0);
        }
    }

    // ---- layer 3 in registers
    float s[4][4];
#pragma unroll
    for (int mt = 0; mt < 4; ++mt)
#pragma unroll
        for (int r = 0; r < 4; ++r)
            s[mt][r] = fsilu(acc2[mt][r] + bias2) * w3v;
#pragma unroll
    for (int off = 1; off < 16; off <<= 1) {
#pragma unroll
        for (int mt = 0; mt < 4; ++mt)
#pragma unroll
            for (int r = 0; r < 4; ++r)
                s[mt][r] += __shfl_xor(s[mt][r], off);
    }
    if (lrow == 0) {
#pragma unroll
        for (int mt = 0; mt < 4; ++mt)
#pragma unroll
            for (int r = 0; r < 4; ++r)
                part[wave][mt * 16 + quad * 4 + r] = s[mt][r];
    }
    __syncthreads();

    if (tid < EPB) {
        float ssum = b3v[0];
#pragma unroll
        for (int w = 0; w < 8; ++w) ssum += part[w][tid];
        att[eb + tid] = fsig(ssum) * emask[eb + tid];
    }
}

// ---------------- Kernel 4: aggregate + node MLP + LNs ----------------
// 256 threads, 8 nodes/block. Gather: 4 quarter-waves split each edge list;
// each wave reads one full 256B line per edge (u32 channel-pair loads).
__global__ __launch_bounds__(256) void node_kernel(
    const float* __restrict__ attv, const int* __restrict__ adj, const int* __restrict__ cnt,
    const int* __restrict__ edges, const unsigned short* __restrict__ xb,
    const float* __restrict__ x,
    const float* __restrict__ w1, const float* __restrict__ bb1,
    const float* __restrict__ lng, const float* __restrict__ lnb,
    const float* __restrict__ w2, const float* __restrict__ bb2,
    const float* __restrict__ gF, const float* __restrict__ bF,
    float* __restrict__ out, int E) {
    __shared__ float atts[NPB][CAP];
    __shared__ int   cols[NPB][CAP];
    __shared__ float parts[4][NPB][128];
    __shared__ float outv[NPB][128];
    __shared__ float bufs[NPB][128];
    __shared__ float mu_s[NPB], rs_s[NPB];
    __shared__ int cnts[NPB];

    int t = threadIdx.x;
    int n0 = blockIdx.x * NPB;

    if (t < NPB) { int c = cnt[n0 + t]; cnts[t] = c > CAP ? CAP : c; }
    __syncthreads();

    // stage lists
#pragma unroll 1
    for (int j = 0; j < NPB; ++j) {
        int c = cnts[j];
        const int* al = adj + (size_t)(n0 + j) * CAP;
        for (int i = t; i < c; i += 256) {
            int e = al[i];
            atts[j][i] = attv[e];
            cols[j][i] = edges[E + e];
        }
    }
    __syncthreads();

    // gather partial sums
    int q = t >> 6, cp = t & 63;
#pragma unroll 1
    for (int j = 0; j < NPB; ++j) {
        int c = cnts[j];
        float a0 = 0.f, b0 = 0.f, a1v = 0.f, b1v = 0.f;
        int i = q;
        for (; i + 4 < c; i += 8) {
            unsigned u0 = *(const unsigned*)&xb[(size_t)cols[j][i] * DIM + cp * 2];
            float w0 = atts[j][i];
            unsigned u1 = *(const unsigned*)&xb[(size_t)cols[j][i + 4] * DIM + cp * 2];
            float w1v = atts[j][i + 4];
            a0 += w0 * bf2f((unsigned short)(u0 & 0xffff));
            b0 += w0 * bf2f((unsigned short)(u0 >> 16));
            a1v += w1v * bf2f((unsigned short)(u1 & 0xffff));
            b1v += w1v * bf2f((unsigned short)(u1 >> 16));
        }
        for (; i < c; i += 4) {
            unsigned u0 = *(const unsigned*)&xb[(size_t)cols[j][i] * DIM + cp * 2];
            float w0 = atts[j][i];
            a0 += w0 * bf2f((unsigned short)(u0 & 0xffff));
            b0 += w0 * bf2f((unsigned short)(u0 >> 16));
        }
        parts[q][j][cp * 2]     = a0 + a1v;
        parts[q][j][cp * 2 + 1] = b0 + b1v;
    }
    __syncthreads();

    // combine + node MLP: thread (h = t>>7, ch = t&127) owns nodes h*4..h*4+3
    int h = t >> 7, ch = t & 127;
    float xres[4];
#pragma unroll
    for (int jj = 0; jj < 4; ++jj) {
        int j = h * 4 + jj;
        outv[j][ch] = (parts[0][j][ch] + parts[1][j][ch] + parts[2][j][ch] + parts[3][j][ch]) * 0.01f;
        xres[jj] = x[(size_t)(n0 + j) * DIM + ch];
    }
    __syncthreads();

    float a1[4] = {0, 0, 0, 0};
    for (int kc = 0; kc < 128; kc += 4) {
        float4 wv = *(const float4*)&w1[(size_t)ch * DIM + kc];
#pragma unroll
        for (int jj = 0; jj < 4; ++jj) {
            int j = h * 4 + jj;
            a1[jj] += wv.x * outv[j][kc] + wv.y * outv[j][kc + 1] + wv.z * outv[j][kc + 2] + wv.w * outv[j][kc + 3];
        }
    }
    float bias1 = bb1[ch];
#pragma unroll
    for (int jj = 0; jj < 4; ++jj) bufs[h * 4 + jj][ch] = a1[jj] + bias1;
    __syncthreads();

    // LN reduction 1: 8 groups of 32 lanes
    {
        int j = t >> 5, l = t & 31;
        float s = 0.f, qq = 0.f;
#pragma unroll
        for (int i = 0; i < 4; ++i) { float v = bufs[j][l + 32 * i]; s += v; qq += v * v; }
#pragma unroll
        for (int off = 16; off; off >>= 1) { s += __shfl_xor(s, off); qq += __shfl_xor(qq, off); }
        if (l == 0) {
            float mu = s * (1.f / 128.f);
            float var = qq * (1.f / 128.f) - mu * mu;
            mu_s[j] = mu; rs_s[j] = rsqrtf(var + 1e-5f);
        }
    }
    __syncthreads();

    float g = lng[ch], bb = lnb[ch];
    float h2[4];
#pragma unroll
    for (int jj = 0; jj < 4; ++jj) {
        int j = h * 4 + jj;
        h2[jj] = fsilu((bufs[j][ch] - mu_s[j]) * rs_s[j] * g + bb);
    }
    __syncthreads();
#pragma unroll
    for (int jj = 0; jj < 4; ++jj) bufs[h * 4 + jj][ch] = h2[jj];
    __syncthreads();

    float a3[4] = {0, 0, 0, 0};
    for (int kc = 0; kc < 128; kc += 4) {
        float4 wv = *(const float4*)&w2[(size_t)ch * DIM + kc];
#pragma unroll
        for (int jj = 0; jj < 4; ++jj) {
            int j = h * 4 + jj;
            a3[jj] += wv.x * bufs[j][kc] + wv.y * bufs[j][kc + 1] + wv.z * bufs[j][kc + 2] + wv.w * bufs[j][kc + 3];
        }
    }
    float bias2 = bb2[ch];
    float hh[4];
#pragma unroll
    for (int jj = 0; jj < 4; ++jj) hh[jj] = a3[jj] + bias2 + xres[jj];
    __syncthreads();
#pragma unroll
    for (int jj = 0; jj < 4; ++jj) bufs[h * 4 + jj][ch] = hh[jj];
    __syncthreads();

    // LN reduction 2
    {
        int j = t >> 5, l = t & 31;
        float s = 0.f, qq = 0.f;
#pragma unroll
        for (int i = 0; i < 4; ++i) { float v = bufs[j][l + 32 * i]; s += v; qq += v * v; }
#pragma unroll
        for (int off = 16; off; off >>= 1) { s += __shfl_xor(s, off); qq += __shfl_xor(qq, off); }
        if (l == 0) {
            float mu = s * (1.f / 128.f);
            float var = qq * (1.f / 128.f) - mu * mu;
            mu_s[j] = mu; rs_s[j] = rsqrtf(var + 1e-5f);
        }
    }
    __syncthreads();

    float gf = gF[ch], bf = bF[ch];
#pragma unroll
    for (int jj = 0; jj < 4; ++jj) {
        int j = h * 4 + jj;
        float y = (hh[jj] - mu_s[j]) * rs_s[j] * gf + bf;
        out[(size_t)(n0 + j) * DIM + ch] = fsilu(y);
    }
}

extern "C" void kernel_launch(void* const* d_in, const int* in_sizes, int n_in,
                              void* d_out, int out_size, void* d_ws, size_t ws_size,
                              hipStream_t stream) {
    const float* h         = (const float*)d_in[0];
    const float* distances = (const float*)d_in[1];
    const float* edge_mask = (const float*)d_in[3];
    const float* lin_w     = (const float*)d_in[4];
    const float* lin_b     = (const float*)d_in[5];
    const float* att_w1    = (const float*)d_in[6];
    const float* att_b1    = (const float*)d_in[7];
    const float* att_w2    = (const float*)d_in[8];
    const float* att_b2    = (const float*)d_in[9];
    const float* att_w3    = (const float*)d_in[10];
    const float* att_b3    = (const float*)d_in[11];
    const float* nm_w1     = (const float*)d_in[12];
    const float* nm_b1     = (const float*)d_in[13];
    const float* nm_ln_g   = (const float*)d_in[14];
    const float* nm_ln_b   = (const float*)d_in[15];
    const float* nm_w2     = (const float*)d_in[16];
    const float* nm_b2     = (const float*)d_in[17];
    const float* ln_g      = (const float*)d_in[18];
    const float* ln_b      = (const float*)d_in[19];
    const int*   edges     = (const int*)d_in[20];
    float* out = (float*)d_out;

    const int N = N_NODES, E = E_EDGES;

    char* ws = (char*)d_ws;
    float* x            = (float*)ws;            ws += (size_t)N * DIM * 4;
    unsigned short* xb  = (unsigned short*)ws;   ws += (size_t)N * DIM * 2;
    float* attv         = (float*)ws;            ws += (size_t)E * 4;
    int* cnt            = (int*)ws;              ws += (size_t)N * 4;
    int* adj            = (int*)ws;              ws += (size_t)N * CAP * 4;
    unsigned short* w1b = (unsigned short*)ws;   ws += 256 * 256 * 2;
    float* w1last       = (float*)ws;            ws += 256 * 4;
    unsigned short* w2b = (unsigned short*)ws;   ws += 128 * 256 * 2;

    hipMemsetAsync(cnt, 0, (size_t)N * 4, stream);

    prep_kernel<<<64, 256, 0, stream>>>(att_w1, att_w2, w1b, w1last, w2b);
    lin_kernel<<<N / 16, 128, 0, stream>>>(h, lin_w, lin_b, x, xb);
    adj_kernel<<<(E + 255) / 256, 256, 0, stream>>>(edges, cnt, adj, E);
    edge_kernel<<<E / EPB, 512, 0, stream>>>(xb, distances, edge_mask, edges,
                                             w1b, w1last, att_b1, w2b, att_b2,
                                             att_w3, att_b3, attv, E);
    node_kernel<<<N / NPB, 256, 0, stream>>>(attv, adj, cnt, edges, xb, x,
                                             nm_w1, nm_b1, nm_ln_g, nm_ln_b,
                                             nm_w2, nm_b2, ln_g, ln_b, out, E);
}